// Round 1
// baseline (928.775 us; speedup 1.0000x reference)
//
#include <hip/hip_runtime.h>
#include <stdint.h>

#define B_  8
#define L_  512
#define Dk  256
#define O_  64
#define DP  257
#define IP  264                 // padded i-dim
#define N1  (O_ * IP)           // 16896
#define M1  (B_ * L_)           // 4096

typedef __attribute__((ext_vector_type(8))) short bf16x8;
typedef __attribute__((ext_vector_type(4))) float f32x4;

__device__ __forceinline__ unsigned short f2bf(float f) {
    union { float f; unsigned u; } v; v.f = f;
    return (unsigned short)((v.u + 0x7fffu + ((v.u >> 16) & 1u)) >> 16);
}
__device__ __forceinline__ float bf2f(unsigned short h) {
    union { unsigned u; float f; } v; v.u = ((unsigned)h) << 16;
    return v.f;
}

// ---- convert x1, x2 (fp32 -> bf16), 4 elems/thread ----
__global__ void cvt_x(const float* __restrict__ x1, const float* __restrict__ x2,
                      unsigned short* __restrict__ x1b, unsigned short* __restrict__ x2b) {
    int idx = blockIdx.x * 256 + threadIdx.x;        // 0 .. 524287
    const int half = (M1 * Dk) / 4;                  // 262144 groups per tensor
    const float4* src; unsigned short* dst; int g;
    if (idx < half) { src = (const float4*)x1; dst = x1b; g = idx; }
    else            { src = (const float4*)x2; dst = x2b; g = idx - half; }
    float4 v = src[g];
    ushort4 w; w.x = f2bf(v.x); w.y = f2bf(v.y); w.z = f2bf(v.z); w.w = f2bf(v.w);
    *(ushort4*)&dst[g * 4] = w;
}

// ---- convert U -> W2 (bf16, rows r=o*264+i, K=256) + Ubias (fp32, j=256 col) ----
__global__ void cvt_u(const float* __restrict__ U, unsigned short* __restrict__ W2,
                      float* __restrict__ Ubias) {
    int t = blockIdx.x * 256 + threadIdx.x;          // N1*64 threads
    int r = t >> 6; int j4 = (t & 63) << 2;
    int o = r / IP, i = r % IP;
    ushort4 w;
    if (i < DP) {
        const float* up = U + ((size_t)o * DP + i) * DP + j4;
        w.x = f2bf(up[0]); w.y = f2bf(up[1]); w.z = f2bf(up[2]); w.w = f2bf(up[3]);
        if (j4 == 0) Ubias[r] = U[((size_t)o * DP + i) * DP + 256];
    } else {
        w.x = w.y = w.z = w.w = 0;
        if (j4 == 0) Ubias[r] = 0.f;
    }
    *(ushort4*)&W2[(size_t)r * Dk + j4] = w;
}

// ---- stage 1: T[4096 x 16896] = x1b[4096 x 256] @ W2[16896 x 256]^T + Ubias ----
// Barrier-free register GEMM: MFMA fragments loaded directly from global (L2).
// XCD-aware placement: each XCD owns 4 m-blocks x all 132 n-panels, m-minor order,
// so a W2 panel (64 KB) is reused by the 4 co-resident m-blocks and read ~once/XCD.
__launch_bounds__(256)
__global__ void gemm1(const unsigned short* __restrict__ A,
                      const unsigned short* __restrict__ Bw,
                      const float* __restrict__ bias,
                      unsigned short* __restrict__ C) {
    const int f = blockIdx.x;                 // 4224 = 8 XCD * (4 m) * (132 n)
    const int xcd = f & 7, idx = f >> 3;
    const int m0 = (xcd * 4 + (idx & 3)) * 128;
    const int n0 = (idx >> 2) * 128;
    const int tid = threadIdx.x, wave = tid >> 6, lane = tid & 63;
    const int wm = (wave >> 1) * 64, wn = (wave & 1) * 64;
    const int lrow = lane & 15, lq = lane >> 4;
    const unsigned short* Ab = A  + (size_t)(m0 + wm + lrow) * Dk + lq * 8;
    const unsigned short* Bb = Bw + (size_t)(n0 + wn + lrow) * Dk + lq * 8;

    f32x4 acc[4][4] = {};
#pragma unroll
    for (int k0 = 0; k0 < Dk; k0 += 32) {
        bf16x8 af[4], bfr[4];
#pragma unroll
        for (int mt = 0; mt < 4; ++mt)
            af[mt] = *(const bf16x8*)(Ab + mt * (16 * Dk) + k0);
#pragma unroll
        for (int nt = 0; nt < 4; ++nt)
            bfr[nt] = *(const bf16x8*)(Bb + nt * (16 * Dk) + k0);
#pragma unroll
        for (int mt = 0; mt < 4; ++mt)
#pragma unroll
            for (int nt = 0; nt < 4; ++nt)
                acc[mt][nt] = __builtin_amdgcn_mfma_f32_16x16x32_bf16(
                    af[mt], bfr[nt], acc[mt][nt], 0, 0, 0);
    }
#pragma unroll
    for (int nt = 0; nt < 4; ++nt) {
        const int n = n0 + wn + nt * 16 + lrow;
        const float bv = bias[n];
#pragma unroll
        for (int mt = 0; mt < 4; ++mt) {
            const int m = m0 + wm + mt * 16 + lq * 4;
#pragma unroll
            for (int r = 0; r < 4; ++r)
                C[(size_t)(m + r) * N1 + n] = f2bf(acc[mt][nt][r] + bv);
        }
    }
}

// ---- stage 2: per (b,l): out[512 x 64] = x2b[b][512 x 256] @ T[b,l][64 x 256]^T + tbias
// Barrier-free register GEMM, block tile 256m x 64o (T read ~once instead of 4x).
// XCD = b: x2b[b] (256 KB) is L2-resident; the two half-tiles of one bl are
// dispatch-adjacent on the same XCD so the T-tile (33 KB) comes from L2 the 2nd time.
__launch_bounds__(256)
__global__ void gemm2(const unsigned short* __restrict__ X2b,
                      const unsigned short* __restrict__ T,
                      float* __restrict__ out) {
    const int f = blockIdx.x;                 // 8192 = 8 XCD * 512 l * 2 m-halves
    const int xcd = f & 7, idx = f >> 3;      // idx 0..1023
    const int b  = xcd;
    const int l  = idx >> 1;
    const int bl = (b << 9) + l;
    const int m0 = (idx & 1) << 8;            // 0 or 256
    const int tid = threadIdx.x, wave = tid >> 6, lane = tid & 63;
    const int wm = wave << 6;                 // waves stack the m dimension
    const int lrow = lane & 15, lq = lane >> 4;
    const unsigned short* Ap = X2b + (size_t)b * (L_ * Dk)
                             + (size_t)(m0 + wm + lrow) * Dk + lq * 8;
    const unsigned short* Tp = T + (size_t)bl * N1;
    const unsigned short* Bp = Tp + (size_t)lrow * IP + lq * 8;

    f32x4 acc[4][4] = {};
#pragma unroll
    for (int k0 = 0; k0 < Dk; k0 += 32) {
        bf16x8 af[4], bfr[4];
#pragma unroll
        for (int mt = 0; mt < 4; ++mt)
            af[mt] = *(const bf16x8*)(Ap + mt * (16 * Dk) + k0);
#pragma unroll
        for (int nt = 0; nt < 4; ++nt)
            bfr[nt] = *(const bf16x8*)(Bp + nt * (16 * IP) + k0);
#pragma unroll
        for (int mt = 0; mt < 4; ++mt)
#pragma unroll
            for (int nt = 0; nt < 4; ++nt)
                acc[mt][nt] = __builtin_amdgcn_mfma_f32_16x16x32_bf16(
                    af[mt], bfr[nt], acc[mt][nt], 0, 0, 0);
    }
    float* op = out + (size_t)bl * (512 * 64);
#pragma unroll
    for (int nt = 0; nt < 4; ++nt) {
        const int o = nt * 16 + lrow;
        const float bv = bf2f(Tp[o * IP + 256]);
#pragma unroll
        for (int mt = 0; mt < 4; ++mt) {
            const int m = m0 + wm + mt * 16 + lq * 4;
#pragma unroll
            for (int r = 0; r < 4; ++r)
                op[(size_t)(m + r) * 64 + o] = acc[mt][nt][r] + bv;
        }
    }
}

extern "C" void kernel_launch(void* const* d_in, const int* in_sizes, int n_in,
                              void* d_out, int out_size, void* d_ws, size_t ws_size,
                              hipStream_t stream) {
    const float* x1 = (const float*)d_in[0];
    const float* x2 = (const float*)d_in[1];
    const float* U  = (const float*)d_in[2];
    float* out = (float*)d_out;

    char* ws = (char*)d_ws;
    unsigned short* x1b  = (unsigned short*)(ws);                       //  2 MiB
    unsigned short* x2b  = (unsigned short*)(ws + 2097152);             //  2 MiB
    unsigned short* W2   = (unsigned short*)(ws + 4194304);             //  8650752 B
    float*          Ubias= (float*)        (ws + 4194304 + 8650752);    //  67584 B
    unsigned short* T    = (unsigned short*)(ws + 4194304 + 8650752 + 67584); // 138412032 B

    hipLaunchKernelGGL(cvt_x, dim3(2048), dim3(256), 0, stream, x1, x2, x1b, x2b);
    hipLaunchKernelGGL(cvt_u, dim3((N1 * 64) / 256), dim3(256), 0, stream, U, W2, Ubias);
    hipLaunchKernelGGL(gemm1, dim3(4224), dim3(256), 0, stream, x1b, W2, Ubias, T);
    hipLaunchKernelGGL(gemm2, dim3(8192), dim3(256), 0, stream, x2b, T, out);
}

// Round 2
// 684.370 us; speedup vs baseline: 1.3571x; 1.3571x over previous
//
#include <hip/hip_runtime.h>
#include <stdint.h>

#define B_  8
#define L_  512
#define Dk  256
#define O_  64
#define DP  257
#define IP  264                 // padded i-dim
#define N1  (O_ * IP)           // 16896
#define M1  (B_ * L_)           // 4096

typedef __attribute__((ext_vector_type(8))) short bf16x8;
typedef __attribute__((ext_vector_type(4))) float f32x4;

__device__ __forceinline__ unsigned short f2bf(float f) {
    union { float f; unsigned u; } v; v.f = f;
    return (unsigned short)((v.u + 0x7fffu + ((v.u >> 16) & 1u)) >> 16);
}
__device__ __forceinline__ float bf2f(unsigned short h) {
    union { unsigned u; float f; } v; v.u = ((unsigned)h) << 16;
    return v.f;
}
__device__ __forceinline__ void gload16(const void* g, void* l) {
    __builtin_amdgcn_global_load_lds(
        (const __attribute__((address_space(1))) unsigned int*)g,
        (__attribute__((address_space(3))) unsigned int*)l, 16, 0, 0);
}

// ---- convert x1, x2 (fp32 -> bf16), 4 elems/thread ----
__global__ void cvt_x(const float* __restrict__ x1, const float* __restrict__ x2,
                      unsigned short* __restrict__ x1b, unsigned short* __restrict__ x2b) {
    int idx = blockIdx.x * 256 + threadIdx.x;        // 0 .. 524287
    const int half = (M1 * Dk) / 4;                  // 262144 groups per tensor
    const float4* src; unsigned short* dst; int g;
    if (idx < half) { src = (const float4*)x1; dst = x1b; g = idx; }
    else            { src = (const float4*)x2; dst = x2b; g = idx - half; }
    float4 v = src[g];
    ushort4 w; w.x = f2bf(v.x); w.y = f2bf(v.y); w.z = f2bf(v.z); w.w = f2bf(v.w);
    *(ushort4*)&dst[g * 4] = w;
}

// ---- convert U -> W2 (bf16, rows r=o*264+i, K=256) + Ubias (fp32, j=256 col) ----
__global__ void cvt_u(const float* __restrict__ U, unsigned short* __restrict__ W2,
                      float* __restrict__ Ubias) {
    int t = blockIdx.x * 256 + threadIdx.x;          // N1*64 threads
    int r = t >> 6; int j4 = (t & 63) << 2;
    int o = r / IP, i = r % IP;
    ushort4 w;
    if (i < DP) {
        const float* up = U + ((size_t)o * DP + i) * DP + j4;
        w.x = f2bf(up[0]); w.y = f2bf(up[1]); w.z = f2bf(up[2]); w.w = f2bf(up[3]);
        if (j4 == 0) Ubias[r] = U[((size_t)o * DP + i) * DP + 256];
    } else {
        w.x = w.y = w.z = w.w = 0;
        if (j4 == 0) Ubias[r] = 0.f;
    }
    *(ushort4*)&W2[(size_t)r * Dk + j4] = w;
}

// ---- stage a [64 rows x 256 col] bf16 tile into LDS, XOR-swizzled ----
// LDS(r, cb) holds src(r, cb ^ ((r&15)<<4))  (cb = byte col, 16B-aligned chunks)
// global_load_lds dest is linear (wave base + lane*16); swizzle done on the
// per-lane GLOBAL source address (rule: both-sides-or-neither, pre-swz source).
__device__ __forceinline__ void stage64(const unsigned short* __restrict__ src,
                                        const int stride /*shorts*/,
                                        unsigned short* lds, const int tid) {
#pragma unroll
    for (int q = 0; q < 4; ++q) {
        const int c = q * 512 + tid;                  // 0..2047 : 16B chunk id
        const int r = c >> 5;                         // row 0..63
        const int sb = ((c & 31) << 4) ^ ((r & 15) << 4);   // swizzled src byte col
        gload16(src + (size_t)r * stride + (sb >> 1),
                &lds[(q * 512 + (tid & 448)) * 8]);   // wave-uniform base
    }
}

// ---- stage 1: T[4096 x 16896] = x1b @ W2^T + Ubias ----
// Block: 128 m-rows of x1b pinned in registers; loop 8 W2 n-tiles (64x256)
// through double-buffered swizzled LDS with counted vmcnt (loads never drained).
__launch_bounds__(512, 4)
__global__ void gemm1(const unsigned short* __restrict__ A,
                      const unsigned short* __restrict__ Bw,
                      const float* __restrict__ bias,
                      unsigned short* __restrict__ C) {
    __shared__ __align__(16) unsigned short lds[2][16384];   // 2 x 32 KiB
    const int tid = threadIdx.x, wid = tid >> 6, lane = tid & 63;
    const int lrow = lane & 15, lq = lane >> 4;
    const int f = blockIdx.x;                 // 1056 = 32 m-panels * 33 chunks
    const int mp = f & 31, chunk = f >> 5;    // chunk 0..32 (8 n-tiles each)
    const int mrow = mp * 128 + wid * 16;     // wave's 16 m-rows
    const unsigned short* Ag = A + (size_t)(mrow + lrow) * Dk + lq * 8;

    bf16x8 areg[8];
#pragma unroll
    for (int ks = 0; ks < 8; ++ks)
        areg[ks] = *(const bf16x8*)(Ag + ks * 32);

    const unsigned short* B0 = Bw + (size_t)chunk * 8 * 64 * Dk;
    stage64(B0, Dk, lds[0], tid);
    __syncthreads();                          // one full drain, then counted waits

    const int swz = lrow << 4;
    for (int it = 0; it < 8; ++it) {
        if (it + 1 < 8)
            stage64(B0 + (size_t)(it + 1) * 64 * Dk, Dk, lds[(it + 1) & 1], tid);
        // 16 stores + 4 fresh loads may stay in flight; current buf's loads done.
        asm volatile("s_waitcnt vmcnt(20)" ::: "memory");
        __builtin_amdgcn_s_barrier();
        const unsigned short* Ts = lds[it & 1];
        f32x4 acc[4] = {};
#pragma unroll
        for (int ks = 0; ks < 8; ++ks)
#pragma unroll
            for (int nt = 0; nt < 4; ++nt) {
                const bf16x8 bfr = *(const bf16x8*)&Ts[((nt * 16 + lrow) << 8)
                                      + ((((ks << 6) + (lq << 4)) ^ swz) >> 1)];
                acc[nt] = __builtin_amdgcn_mfma_f32_16x16x32_bf16(
                    areg[ks], bfr, acc[nt], 0, 0, 0);
            }
        const int n0 = (chunk * 8 + it) * 64;
#pragma unroll
        for (int nt = 0; nt < 4; ++nt) {
            const int n = n0 + nt * 16 + lrow;
            const float bv = bias[n];
#pragma unroll
            for (int r = 0; r < 4; ++r)
                C[(size_t)(mrow + lq * 4 + r) * N1 + n] = f2bf(acc[nt][r] + bv);
        }
        __builtin_amdgcn_s_barrier();         // protect buf before restage
    }
}

// ---- stage 2: out[bl, 0:512, 0:64] = x2b[b] @ T[bl]^T + tbias ----
// Block: (b, m-panel of 128, l-group of 8). A-panel in registers (x2b[b] is
// L2-resident per-XCD); loop 8 l's, T-tile (64x256) double-buffered in LDS.
__launch_bounds__(512, 4)
__global__ void gemm2(const unsigned short* __restrict__ X2b,
                      const unsigned short* __restrict__ T,
                      float* __restrict__ out) {
    __shared__ __align__(16) unsigned short lds[2][16384];
    const int tid = threadIdx.x, wid = tid >> 6, lane = tid & 63;
    const int lrow = lane & 15, lq = lane >> 4;
    const int f = blockIdx.x;                 // 2048 = 4 mp * 512 (b,lg)
    const int mp = f & 3;
    const int lgb = f >> 2;                   // 0..511
    const int b = lgb >> 6, lg = lgb & 63;
    const int bl0 = b * 512 + lg * 8;
    const int mrow = mp * 128 + wid * 16;
    const unsigned short* Ag = X2b + ((size_t)b * L_ + mrow + lrow) * Dk + lq * 8;

    bf16x8 areg[8];
#pragma unroll
    for (int ks = 0; ks < 8; ++ks)
        areg[ks] = *(const bf16x8*)(Ag + ks * 32);

    const unsigned short* T0 = T + (size_t)bl0 * N1;
    stage64(T0, IP, lds[0], tid);
    __syncthreads();

    const int swz = lrow << 4;
    for (int it = 0; it < 8; ++it) {
        if (it + 1 < 8)
            stage64(T0 + (size_t)(it + 1) * N1, IP, lds[(it + 1) & 1], tid);
        asm volatile("s_waitcnt vmcnt(20)" ::: "memory");
        __builtin_amdgcn_s_barrier();
        const unsigned short* Ts = lds[it & 1];
        f32x4 acc[4] = {};
#pragma unroll
        for (int ks = 0; ks < 8; ++ks)
#pragma unroll
            for (int nt = 0; nt < 4; ++nt) {
                const bf16x8 bfr = *(const bf16x8*)&Ts[((nt * 16 + lrow) << 8)
                                      + ((((ks << 6) + (lq << 4)) ^ swz) >> 1)];
                acc[nt] = __builtin_amdgcn_mfma_f32_16x16x32_bf16(
                    areg[ks], bfr, acc[nt], 0, 0, 0);
            }
        const unsigned short* Tg = T0 + (size_t)it * N1;
        float* Og = out + ((size_t)(bl0 + it) * 512 + mrow + lq * 4) * 64;
#pragma unroll
        for (int nt = 0; nt < 4; ++nt) {
            const int o = nt * 16 + lrow;
            const float bv = bf2f(Tg[(size_t)o * IP + 256]);
#pragma unroll
            for (int r = 0; r < 4; ++r)
                Og[(size_t)r * 64 + o] = acc[nt][r] + bv;
        }
        __builtin_amdgcn_s_barrier();
    }
}

extern "C" void kernel_launch(void* const* d_in, const int* in_sizes, int n_in,
                              void* d_out, int out_size, void* d_ws, size_t ws_size,
                              hipStream_t stream) {
    const float* x1 = (const float*)d_in[0];
    const float* x2 = (const float*)d_in[1];
    const float* U  = (const float*)d_in[2];
    float* out = (float*)d_out;

    char* ws = (char*)d_ws;
    unsigned short* x1b  = (unsigned short*)(ws);                       //  2 MiB
    unsigned short* x2b  = (unsigned short*)(ws + 2097152);             //  2 MiB
    unsigned short* W2   = (unsigned short*)(ws + 4194304);             //  8650752 B
    float*          Ubias= (float*)        (ws + 4194304 + 8650752);    //  67584 B
    unsigned short* T    = (unsigned short*)(ws + 4194304 + 8650752 + 67584); // 138412032 B

    hipLaunchKernelGGL(cvt_x, dim3(2048), dim3(256), 0, stream, x1, x2, x1b, x2b);
    hipLaunchKernelGGL(cvt_u, dim3((N1 * 64) / 256), dim3(256), 0, stream, U, W2, Ubias);
    hipLaunchKernelGGL(gemm1, dim3(1056), dim3(512), 0, stream, x1b, W2, Ubias, T);
    hipLaunchKernelGGL(gemm2, dim3(2048), dim3(512), 0, stream, x2b, T, out);
}